// Round 13
// baseline (599.148 us; speedup 1.0000x reference)
//
#include <hip/hip_runtime.h>
#include <cfloat>

#define BB 64
#define NPERB 2048
#define KNN 16
#define NTOT (BB*NPERB)
#define NCAND 24

typedef __bf16 bf16x8 __attribute__((ext_vector_type(8)));
typedef float  f32x4  __attribute__((ext_vector_type(4)));

__device__ __forceinline__ unsigned int med3u(unsigned int a, unsigned int b, unsigned int c) {
    unsigned int d;
    asm("v_med3_u32 %0, %1, %2, %3" : "=v"(d) : "v"(a), "v"(b), "v"(c));
    return d;
}

__device__ __forceinline__ unsigned short bf16rn(float f) {
    unsigned int u = __float_as_uint(f);
    u += 0x7fffu + ((u >> 16) & 1u);
    return (unsigned short)(u >> 16);
}
__device__ __forceinline__ unsigned int pk2(float a, float b) {
    return ((unsigned int)bf16rn(b) << 16) | (unsigned int)bf16rn(a);
}

// Kernel 1 (R13 rewrite): inverted GEMM mapping.
// Old version: every thread re-read all 32KB of weights from LDS as wave-uniform
// b128 reads -> 2048 LDS instrs/thread, LDS-issue-bound (~24.6K cyc/wave vs
// 16.4K fma cyc). New: lane owns output column o=lane, weights in VGPRs
// (wmr[64], w2r[64], loaded once from a padded LDS transpose, conflict-free);
// each wave walks 64 rows with x read as wave-uniform global loads (scalar pipe).
// Numerics: phase A (sqnp np-tree, pk2 bytes) byte-identical; GEMM chains
// value-identical (ascending f, single accumulator, w1m = w1 - w2 same fsub,
// bias added last). Only operand residency/instruction selection changes.
__global__ __launch_bounds__(256) void k_transform(const float4* __restrict__ x4,
    const float* __restrict__ w, const float* __restrict__ bias,
    float* __restrict__ Aout, float* __restrict__ Bvv, float* __restrict__ sqnp,
    uint4* __restrict__ xbu4)
{
    __shared__ __align__(16) float wt1[64*65];   // w1 transposed [f][o], +1 pad
    __shared__ __align__(16) float wt2[64*65];   // w2 transposed [f][o], +1 pad
    const int t = threadIdx.x;
    const int r = blockIdx.x * 256 + t;

    // stage W transposed: [f*65 + o] (pad breaks the f-major bank aliasing;
    // write banks (f+o)%32 across lanes of same o-group -> conflict-free-ish,
    // one-time cost)
#pragma unroll
    for (int i = 0; i < 16; ++i) {
        int e = t + i*256;
        int o = e >> 6, f = e & 63;
        wt1[f*65 + o] = w[o*128 + f];
        wt2[f*65 + o] = w[o*128 + 64 + f];
    }

    // ---- phase A: per-thread own row (byte-identical to R9..R12) ----
    float xr[64];
#pragma unroll
    for (int j = 0; j < 16; ++j) {
        float4 v = x4[(size_t)r * 16 + j];
        xr[4*j+0] = v.x; xr[4*j+1] = v.y; xr[4*j+2] = v.z; xr[4*j+3] = v.w;
    }

    // numpy pairwise-order sum of squares (unchanged op tree)
    {
        float rr[8];
#pragma unroll
        for (int j = 0; j < 8; ++j) rr[j] = __fmul_rn(xr[j], xr[j]);
#pragma unroll
        for (int i = 1; i < 8; ++i)
#pragma unroll
            for (int j = 0; j < 8; ++j)
                rr[j] = __fadd_rn(rr[j], __fmul_rn(xr[8*i + j], xr[8*i + j]));
        float t01 = __fadd_rn(rr[0], rr[1]);
        float t23 = __fadd_rn(rr[2], rr[3]);
        float t45 = __fadd_rn(rr[4], rr[5]);
        float t67 = __fadd_rn(rr[6], rr[7]);
        sqnp[r] = __fadd_rn(__fadd_rn(t01, t23), __fadd_rn(t45, t67));
    }

    // bf16 copy (identical bytes)
#pragma unroll
    for (int i = 0; i < 8; ++i) {
        uint4 u;
        u.x = pk2(xr[8*i+0], xr[8*i+1]);
        u.y = pk2(xr[8*i+2], xr[8*i+3]);
        u.z = pk2(xr[8*i+4], xr[8*i+5]);
        u.w = pk2(xr[8*i+6], xr[8*i+7]);
        xbu4[(size_t)r * 8 + i] = u;
    }

    __syncthreads();   // weight transpose staged

    // ---- load this lane's weight column into registers (once) ----
    const int lane = t & 63;
    const int wv = t >> 6;
    float wmr[64], w2r[64];
#pragma unroll
    for (int f = 0; f < 64; ++f) {
        float w1v = wt1[f*65 + lane];     // banks (f+lane)%32: conflict-free
        float w2v = wt2[f*65 + lane];
        wmr[f] = __fsub_rn(w1v, w2v);     // same values as old wm[]
        w2r[f] = w2v;
    }
    const float biasv = bias[lane];

    // ---- phase B: wave walks its 64 rows; x via wave-uniform loads ----
    const int row0 = blockIdx.x * 256 + wv * 64;
    for (int rr = 0; rr < 64; ++rr) {
        const int row = row0 + rr;
        const float4* xrow = x4 + (size_t)row * 16;   // uniform address
        float a1 = 0.f, a2 = 0.f;
#pragma unroll
        for (int j = 0; j < 16; ++j) {
            float4 xv = xrow[j];
            a1 = __builtin_fmaf(xv.x, wmr[4*j+0], a1); a2 = __builtin_fmaf(xv.x, w2r[4*j+0], a2);
            a1 = __builtin_fmaf(xv.y, wmr[4*j+1], a1); a2 = __builtin_fmaf(xv.y, w2r[4*j+1], a2);
            a1 = __builtin_fmaf(xv.z, wmr[4*j+2], a1); a2 = __builtin_fmaf(xv.z, w2r[4*j+2], a2);
            a1 = __builtin_fmaf(xv.w, wmr[4*j+3], a1); a2 = __builtin_fmaf(xv.w, w2r[4*j+3], a2);
        }
        Aout[(size_t)row*64 + lane] = __fadd_rn(a1, biasv);   // coalesced b32
        Bvv [(size_t)row*64 + lane] = a2;
    }
}

// Kernel 2: byte-identical to R12 (366us measured; prefetch-at-top 2x-unrolled
// dbuf + (256,5)). Known mild spill (WRITE 79.9MB) tolerated — (256,4) retry
// risks the 5-block occupancy; not touched this round.
__global__ __launch_bounds__(256, 5) void k_topk(const float4* __restrict__ x4,
    const uint4* __restrict__ xb, const float* __restrict__ sq, int* __restrict__ nbr)
{
    // phase1: bsh0 0..9216 | bsh1 9216..18432 | rsh 18432..27648 | sqc 27648..28160
    // phase2: cand 0..17408 | cand24 17408..20480
    __shared__ __align__(16) char smem[28160];
    unsigned short* bsh0 = (unsigned short*)smem;
    unsigned short* bsh1 = (unsigned short*)(smem + 9216);
    unsigned short* rsh  = (unsigned short*)(smem + 18432);
    float* sqc           = (float*)(smem + 27648);     // [2][64]
    unsigned int* cand   = (unsigned int*)smem;        // 64 rows x 68
    unsigned short* cand24 = (unsigned short*)(smem + 17408);

    int t = threadIdx.x;
    int lane = t & 63;
    int w = t >> 6;
    int ln = lane & 15, qd = lane >> 4;
    int batch = blockIdx.x >> 5;
    int strip = blockIdx.x & 31;
    int rbase = batch * NPERB;
    int r0g = rbase + strip * 64;

    unsigned int ks[16];
#pragma unroll
    for (int j = 0; j < 16; ++j) ks[j] = 0xFFFFFFFFu;

    // --- helpers (static indexing; no runtime-indexed reg arrays) ---
    auto issue_load = [&](int ct_, uint4& p0, uint4& p1, float& sp) {
        const uint4* src = xb + ((size_t)rbase + ct_*64) * 8;
        p0 = src[t]; p1 = src[t + 256];
        sp = (t < 64) ? sq[rbase + ct_*64 + t] : 0.f;
    };
    auto stage_write = [&](int ct_, uint4 p0, uint4 p1, float sp) {
        // writes tile (ct_+1) held in regs -> buf[(ct_+1)&1]
        unsigned short* bnext = ((ct_ + 1) & 1) ? bsh1 : bsh0;
        *(uint4*)&bnext[(t >> 3)*72 + (t & 7)*8] = p0;
        int l1 = t + 256;
        *(uint4*)&bnext[(l1 >> 3)*72 + (l1 & 7)*8] = p1;
        if (t < 64) sqc[((ct_ + 1) & 1)*64 + t] = sp;
    };

    // --- prologue ---
    {
        const uint4* src = xb + (size_t)r0g * 8;
#pragma unroll
        for (int i = 0; i < 2; ++i) {
            int l = t + i*256;
            uint4 v = src[l];
            *(uint4*)&rsh[(l >> 3)*72 + (l & 7)*8] = v;
        }
    }
    uint4 pA0, pA1, pB0, pB1; float sA, sB;
    issue_load(0, pA0, pA1, sA);
    __syncthreads();
    bf16x8 rf0 = *(const bf16x8*)&rsh[(w*16 + ln)*72 + qd*8];
    bf16x8 rf1 = *(const bf16x8*)&rsh[(w*16 + ln)*72 + 32 + qd*8];
    float sqr16 = sq[r0g + w*16 + ln] + 16.f;

    stage_write(-1, pA0, pA1, sA);      // tile0 -> bsh0, sqc[0]
    issue_load(1, pA0, pA1, sA);        // A := tile1
    __syncthreads();

    // --- main loop, 2x unrolled: invariant at even ct: buf[ct&1]=tile ct, A=tile ct+1 ---
    auto compute_tile = [&](int ct_, const unsigned short* bcur, const float* sqcur) {
#pragma unroll
        for (int ct2 = 0; ct2 < 4; ++ct2) {
            int pt = ct2*16 + ln;
            bf16x8 a0 = *(const bf16x8*)&bcur[pt*72 + qd*8];
            bf16x8 a1 = *(const bf16x8*)&bcur[pt*72 + 32 + qd*8];
            f32x4 acc = {0.f, 0.f, 0.f, 0.f};
            acc = __builtin_amdgcn_mfma_f32_16x16x32_bf16(a0, rf0, acc, 0, 0, 0);
            acc = __builtin_amdgcn_mfma_f32_16x16x32_bf16(a1, rf1, acc, 0, 0, 0);
            f32x4 sc4 = *(const f32x4*)&sqcur[ct2*16 + qd*4];
            int idxb = ct_*64 + ct2*16 + qd*4;
#pragma unroll
            for (int j = 0; j < 4; ++j) {
                float s = fmaf(-2.f, acc[j], sc4[j] + sqr16);   // > 0 always
                unsigned int u = (__float_as_uint(s) & 0xFFFFF800u) | (unsigned int)(idxb + j);
#pragma unroll
                for (int jj = 15; jj >= 1; --jj) ks[jj] = med3u(u, ks[jj-1], ks[jj]);
                ks[0] = min(ks[0], u);
            }
        }
    };

    for (int ct = 0; ct < 32; ct += 2) {
        // even half: compute tile ct (buf0), A holds tile ct+1, issue B := tile ct+2
        if (ct + 2 <= 31) issue_load(ct + 2, pB0, pB1, sB);
        compute_tile(ct, bsh0, sqc);
        stage_write(ct, pA0, pA1, sA);              // tile ct+1 -> bsh1 (ct<=30 always)
        __syncthreads();
        // odd half: compute tile ct+1 (buf1), B holds tile ct+2, issue A := tile ct+3
        if (ct + 3 <= 31) issue_load(ct + 3, pA0, pA1, sA);
        compute_tile(ct + 1, bsh1, sqc + 64);
        if (ct + 1 < 31) stage_write(ct + 1, pB0, pB1, sB);   // tile ct+2 -> bsh0
        __syncthreads();
    }

    // dump per-lane keys
    {
        int r = w*16 + ln;
#pragma unroll
        for (int j = 0; j < 16; ++j) cand[r*68 + qd*16 + j] = ks[j];
    }
    __syncthreads();

    // merge to bf16-top-24 per row
    if (t < 64) {
        unsigned int m24[NCAND];
#pragma unroll
        for (int j = 0; j < NCAND; ++j) m24[j] = 0xFFFFFFFFu;
        for (int i = 0; i < 64; ++i) {
            unsigned int u = cand[t*68 + i];
#pragma unroll
            for (int jj = NCAND-1; jj >= 1; --jj) m24[jj] = med3u(u, m24[jj-1], m24[jj]);
            m24[0] = min(m24[0], u);
        }
#pragma unroll
        for (int j = 0; j < NCAND; ++j) cand24[t*NCAND + j] = (unsigned short)(m24[j] & 0x7FFu);
    }
    __syncthreads();

    // np-exact rescore (R6-verified chain): 4 groups x 6 candidates per row
    {
        int r = t & 63, grp = t >> 6;
        float sqr = sq[r0g + r];
        float4 xrA[8];
#pragma unroll
        for (int i = 0; i < 8; ++i) xrA[i] = x4[(size_t)(r0g + r)*16 + i];
        float* kdf = (float*)cand;
#pragma unroll
        for (int m6 = 0; m6 < 6; ++m6) {
            int m = grp*6 + m6;
            int c = (int)cand24[r*NCAND + m];
            const float4* xb4 = &x4[(size_t)(rbase + c)*16];
            float dot = 0.f;
#pragma unroll
            for (int i = 0; i < 8; ++i) {
                float4 a = xrA[i]; float4 b = xb4[i];
                dot = fmaf(a.x, b.x, dot); dot = fmaf(a.y, b.y, dot);
                dot = fmaf(a.z, b.z, dot); dot = fmaf(a.w, b.w, dot);
            }
#pragma unroll
            for (int i = 8; i < 16; ++i) {
                float4 a = x4[(size_t)(r0g + r)*16 + i]; float4 b = xb4[i];
                dot = fmaf(a.x, b.x, dot); dot = fmaf(a.y, b.y, dot);
                dot = fmaf(a.z, b.z, dot); dot = fmaf(a.w, b.w, dot);
            }
            float kd = __fsub_rn(__fadd_rn(sqr, sq[rbase + c]), __fmul_rn(2.0f, dot));
            kdf[r*68 + m] = kd;
            cand[r*68 + 32 + m] = (unsigned int)c;
        }
    }
    __syncthreads();

    // exact top-16 with (key, idx) ordering
    if (t < 64) {
        float* kdf = (float*)cand;
        float dk[KNN]; int di[KNN];
#pragma unroll
        for (int j = 0; j < KNN; ++j) { dk[j] = FLT_MAX; di[j] = 0x7fffffff; }
        for (int m = 0; m < NCAND; ++m) {
            float kd = kdf[t*68 + m];
            int c = (int)cand[t*68 + 32 + m];
            bool better = (kd < dk[KNN-1]) || (kd == dk[KNN-1] && c < di[KNN-1]);
            if (better) {
#pragma unroll
                for (int j = KNN-1; j >= 1; --j) {
                    bool sh = (dk[j-1] > kd) || (dk[j-1] == kd && di[j-1] > c);
                    bool pl = (!sh) && ((dk[j] > kd) || (dk[j] == kd && di[j] > c));
                    float nk = sh ? dk[j-1] : (pl ? kd : dk[j]);
                    int ni = sh ? di[j-1] : (pl ? c : di[j]);
                    dk[j] = nk; di[j] = ni;
                }
                if ((dk[0] > kd) || (dk[0] == kd && di[0] > c)) { dk[0] = kd; di[0] = c; }
            }
        }
#pragma unroll
        for (int k = 0; k < KNN; ++k) nbr[(size_t)(r0g + t)*16 + k] = di[k];
    }
}

// Kernel 3: out[n,o] = relu(out[n,o] + max_k Bv[nbr_k, o])   (out holds A from k1)
__global__ __launch_bounds__(256) void k_combine(const float* __restrict__ Bvv,
    const int* __restrict__ nbr, float* __restrict__ out)
{
    int t = threadIdx.x;
    int row = blockIdx.x*4 + (t >> 6);
    int o = t & 63;
    int rb = (row >> 11) << 11;
    float m = -FLT_MAX;
#pragma unroll
    for (int k = 0; k < 16; ++k) {
        int c = nbr[(size_t)row*16 + k];
        m = fmaxf(m, Bvv[(size_t)(rb + c)*64 + o]);
    }
    out[(size_t)row*64 + o] = fmaxf(out[(size_t)row*64 + o] + m, 0.f);
}

extern "C" void kernel_launch(void* const* d_in, const int* in_sizes, int n_in,
                              void* d_out, int out_size, void* d_ws, size_t ws_size,
                              hipStream_t stream) {
    const float* x    = (const float*)d_in[0];
    // d_in[1] = batch (contiguous per batch; unused)
    const float* w    = (const float*)d_in[2];
    const float* bias = (const float*)d_in[3];
    float* out = (float*)d_out;

    float* Bvv  = (float*)d_ws;                       // 32 MB
    float* sqnp = Bvv + (size_t)NTOT * 64;            // 0.5 MB
    int*   nbr  = (int*)(sqnp + NTOT);                // 8 MB
    unsigned int* xbu = (unsigned int*)(nbr + (size_t)NTOT * 16);   // 16 MB bf16 x

    k_transform<<<NTOT/256, 256, 0, stream>>>((const float4*)x, w, bias, out, Bvv, sqnp, (uint4*)xbu);
    k_topk<<<2048, 256, 0, stream>>>((const float4*)x, (const uint4*)xbu, sqnp, nbr);
    k_combine<<<NTOT/4, 256, 0, stream>>>(Bvv, nbr, out);
}

// Round 14
// 578.301 us; speedup vs baseline: 1.0360x; 1.0360x over previous
//
#include <hip/hip_runtime.h>
#include <cfloat>

#define BB 64
#define NPERB 2048
#define KNN 16
#define NTOT (BB*NPERB)
#define NCAND 24

typedef __bf16 bf16x8 __attribute__((ext_vector_type(8)));
typedef float  f32x4  __attribute__((ext_vector_type(4)));

__device__ __forceinline__ unsigned int med3u(unsigned int a, unsigned int b, unsigned int c) {
    unsigned int d;
    asm("v_med3_u32 %0, %1, %2, %3" : "=v"(d) : "v"(a), "v"(b), "v"(c));
    return d;
}

__device__ __forceinline__ unsigned short bf16rn(float f) {
    unsigned int u = __float_as_uint(f);
    u += 0x7fffu + ((u >> 16) & 1u);
    return (unsigned short)(u >> 16);
}
__device__ __forceinline__ unsigned int pk2(float a, float b) {
    return ((unsigned int)bf16rn(b) << 16) | (unsigned int)bf16rn(a);
}

// Kernel 1: REVERTED to the R12-measured version (part of the 531us best).
// W staged in LDS [o][f], read as wave-uniform b128 broadcasts.
// R13 lesson: weight-column-in-VGPR mapping (128 regs/thread) kills occupancy
// -> latency-bound at ~196us. LDS-broadcast version is the measured optimum.
__global__ __launch_bounds__(256) void k_transform(const float4* __restrict__ x4,
    const float* __restrict__ w, const float* __restrict__ bias,
    float* __restrict__ Aout, float* __restrict__ Bvv, float* __restrict__ sqnp,
    uint4* __restrict__ xbu4)
{
    __shared__ __align__(16) float wm[64*64];    // (w1-w2)[o][f]
    __shared__ __align__(16) float w2m[64*64];   // w2[o][f]
    const int t = threadIdx.x;
    const int r = blockIdx.x * 256 + t;

#pragma unroll
    for (int i = 0; i < 16; ++i) {
        int e = t + i*256;
        int o = e >> 6, f = e & 63;
        float w1 = w[o*128 + f];
        float w2 = w[o*128 + 64 + f];
        wm[e]  = w1 - w2;
        w2m[e] = w2;
    }

    float xr[64];
#pragma unroll
    for (int j = 0; j < 16; ++j) {
        float4 v = x4[(size_t)r * 16 + j];
        xr[4*j+0] = v.x; xr[4*j+1] = v.y; xr[4*j+2] = v.z; xr[4*j+3] = v.w;
    }

    // numpy pairwise-order sum of squares (unchanged op tree)
    {
        float rr[8];
#pragma unroll
        for (int j = 0; j < 8; ++j) rr[j] = __fmul_rn(xr[j], xr[j]);
#pragma unroll
        for (int i = 1; i < 8; ++i)
#pragma unroll
            for (int j = 0; j < 8; ++j)
                rr[j] = __fadd_rn(rr[j], __fmul_rn(xr[8*i + j], xr[8*i + j]));
        float t01 = __fadd_rn(rr[0], rr[1]);
        float t23 = __fadd_rn(rr[2], rr[3]);
        float t45 = __fadd_rn(rr[4], rr[5]);
        float t67 = __fadd_rn(rr[6], rr[7]);
        sqnp[r] = __fadd_rn(__fadd_rn(t01, t23), __fadd_rn(t45, t67));
    }

    // bf16 copy (identical bytes)
#pragma unroll
    for (int i = 0; i < 8; ++i) {
        uint4 u;
        u.x = pk2(xr[8*i+0], xr[8*i+1]);
        u.y = pk2(xr[8*i+2], xr[8*i+3]);
        u.z = pk2(xr[8*i+4], xr[8*i+5]);
        u.w = pk2(xr[8*i+6], xr[8*i+7]);
        xbu4[(size_t)r * 8 + i] = u;
    }

    __syncthreads();   // weights staged

    for (int o = 0; o < 64; o += 4) {
        float a4[4], b4[4];
#pragma unroll
        for (int oo = 0; oo < 4; ++oo) {
            const float* wmr  = &wm [(o + oo)*64];
            const float* w2mr = &w2m[(o + oo)*64];
            float a1 = 0.f, a2 = 0.f;
#pragma unroll
            for (int fi = 0; fi < 16; ++fi) {
                f32x4 wa = *(const f32x4*)&wmr [fi*4];
                f32x4 wb = *(const f32x4*)&w2mr[fi*4];
#pragma unroll
                for (int k = 0; k < 4; ++k) {
                    float xv = xr[fi*4 + k];
                    a1 = __builtin_fmaf(xv, wa[k], a1);
                    a2 = __builtin_fmaf(xv, wb[k], a2);
                }
            }
            a4[oo] = __fadd_rn(a1, bias[o + oo]);
            b4[oo] = a2;
        }
        *(float4*)&Aout[(size_t)r * 64 + o] = make_float4(a4[0], a4[1], a4[2], a4[3]);
        *(float4*)&Bvv [(size_t)r * 64 + o] = make_float4(b4[0], b4[1], b4[2], b4[3]);
    }
}

// Kernel 2: R12 loop structure (prefetch-at-top, 2x-unrolled dbuf) with ONE
// knob changed: __launch_bounds__ (256,5) -> (256,4). R12's (256,5) made the
// compiler squeeze to 48 VGPR and spill (WRITE 79.9MB vs 24.6 baseline).
// (256,4) gives a 128-VGPR budget -> no spills; costs at most 1 block/CU.
// A/B: if this regresses vs 366us, revert to (256,5).
__global__ __launch_bounds__(256, 4) void k_topk(const float4* __restrict__ x4,
    const uint4* __restrict__ xb, const float* __restrict__ sq, int* __restrict__ nbr)
{
    // phase1: bsh0 0..9216 | bsh1 9216..18432 | rsh 18432..27648 | sqc 27648..28160
    // phase2: cand 0..17408 | cand24 17408..20480
    __shared__ __align__(16) char smem[28160];
    unsigned short* bsh0 = (unsigned short*)smem;
    unsigned short* bsh1 = (unsigned short*)(smem + 9216);
    unsigned short* rsh  = (unsigned short*)(smem + 18432);
    float* sqc           = (float*)(smem + 27648);     // [2][64]
    unsigned int* cand   = (unsigned int*)smem;        // 64 rows x 68
    unsigned short* cand24 = (unsigned short*)(smem + 17408);

    int t = threadIdx.x;
    int lane = t & 63;
    int w = t >> 6;
    int ln = lane & 15, qd = lane >> 4;
    int batch = blockIdx.x >> 5;
    int strip = blockIdx.x & 31;
    int rbase = batch * NPERB;
    int r0g = rbase + strip * 64;

    unsigned int ks[16];
#pragma unroll
    for (int j = 0; j < 16; ++j) ks[j] = 0xFFFFFFFFu;

    // --- helpers (static indexing; no runtime-indexed reg arrays) ---
    auto issue_load = [&](int ct_, uint4& p0, uint4& p1, float& sp) {
        const uint4* src = xb + ((size_t)rbase + ct_*64) * 8;
        p0 = src[t]; p1 = src[t + 256];
        sp = (t < 64) ? sq[rbase + ct_*64 + t] : 0.f;
    };
    auto stage_write = [&](int ct_, uint4 p0, uint4 p1, float sp) {
        // writes tile (ct_+1) held in regs -> buf[(ct_+1)&1]
        unsigned short* bnext = ((ct_ + 1) & 1) ? bsh1 : bsh0;
        *(uint4*)&bnext[(t >> 3)*72 + (t & 7)*8] = p0;
        int l1 = t + 256;
        *(uint4*)&bnext[(l1 >> 3)*72 + (l1 & 7)*8] = p1;
        if (t < 64) sqc[((ct_ + 1) & 1)*64 + t] = sp;
    };

    // --- prologue ---
    {
        const uint4* src = xb + (size_t)r0g * 8;
#pragma unroll
        for (int i = 0; i < 2; ++i) {
            int l = t + i*256;
            uint4 v = src[l];
            *(uint4*)&rsh[(l >> 3)*72 + (l & 7)*8] = v;
        }
    }
    uint4 pA0, pA1, pB0, pB1; float sA, sB;
    issue_load(0, pA0, pA1, sA);
    __syncthreads();
    bf16x8 rf0 = *(const bf16x8*)&rsh[(w*16 + ln)*72 + qd*8];
    bf16x8 rf1 = *(const bf16x8*)&rsh[(w*16 + ln)*72 + 32 + qd*8];
    float sqr16 = sq[r0g + w*16 + ln] + 16.f;

    stage_write(-1, pA0, pA1, sA);      // tile0 -> bsh0, sqc[0]
    issue_load(1, pA0, pA1, sA);        // A := tile1
    __syncthreads();

    // --- main loop, 2x unrolled: invariant at even ct: buf[ct&1]=tile ct, A=tile ct+1 ---
    auto compute_tile = [&](int ct_, const unsigned short* bcur, const float* sqcur) {
#pragma unroll
        for (int ct2 = 0; ct2 < 4; ++ct2) {
            int pt = ct2*16 + ln;
            bf16x8 a0 = *(const bf16x8*)&bcur[pt*72 + qd*8];
            bf16x8 a1 = *(const bf16x8*)&bcur[pt*72 + 32 + qd*8];
            f32x4 acc = {0.f, 0.f, 0.f, 0.f};
            acc = __builtin_amdgcn_mfma_f32_16x16x32_bf16(a0, rf0, acc, 0, 0, 0);
            acc = __builtin_amdgcn_mfma_f32_16x16x32_bf16(a1, rf1, acc, 0, 0, 0);
            f32x4 sc4 = *(const f32x4*)&sqcur[ct2*16 + qd*4];
            int idxb = ct_*64 + ct2*16 + qd*4;
#pragma unroll
            for (int j = 0; j < 4; ++j) {
                float s = fmaf(-2.f, acc[j], sc4[j] + sqr16);   // > 0 always
                unsigned int u = (__float_as_uint(s) & 0xFFFFF800u) | (unsigned int)(idxb + j);
#pragma unroll
                for (int jj = 15; jj >= 1; --jj) ks[jj] = med3u(u, ks[jj-1], ks[jj]);
                ks[0] = min(ks[0], u);
            }
        }
    };

    for (int ct = 0; ct < 32; ct += 2) {
        // even half: compute tile ct (buf0), A holds tile ct+1, issue B := tile ct+2
        if (ct + 2 <= 31) issue_load(ct + 2, pB0, pB1, sB);
        compute_tile(ct, bsh0, sqc);
        stage_write(ct, pA0, pA1, sA);              // tile ct+1 -> bsh1 (ct<=30 always)
        __syncthreads();
        // odd half: compute tile ct+1 (buf1), B holds tile ct+2, issue A := tile ct+3
        if (ct + 3 <= 31) issue_load(ct + 3, pA0, pA1, sA);
        compute_tile(ct + 1, bsh1, sqc + 64);
        if (ct + 1 < 31) stage_write(ct + 1, pB0, pB1, sB);   // tile ct+2 -> bsh0
        __syncthreads();
    }

    // dump per-lane keys
    {
        int r = w*16 + ln;
#pragma unroll
        for (int j = 0; j < 16; ++j) cand[r*68 + qd*16 + j] = ks[j];
    }
    __syncthreads();

    // merge to bf16-top-24 per row
    if (t < 64) {
        unsigned int m24[NCAND];
#pragma unroll
        for (int j = 0; j < NCAND; ++j) m24[j] = 0xFFFFFFFFu;
        for (int i = 0; i < 64; ++i) {
            unsigned int u = cand[t*68 + i];
#pragma unroll
            for (int jj = NCAND-1; jj >= 1; --jj) m24[jj] = med3u(u, m24[jj-1], m24[jj]);
            m24[0] = min(m24[0], u);
        }
#pragma unroll
        for (int j = 0; j < NCAND; ++j) cand24[t*NCAND + j] = (unsigned short)(m24[j] & 0x7FFu);
    }
    __syncthreads();

    // np-exact rescore (R6-verified chain): 4 groups x 6 candidates per row
    {
        int r = t & 63, grp = t >> 6;
        float sqr = sq[r0g + r];
        float4 xrA[8];
#pragma unroll
        for (int i = 0; i < 8; ++i) xrA[i] = x4[(size_t)(r0g + r)*16 + i];
        float* kdf = (float*)cand;
#pragma unroll
        for (int m6 = 0; m6 < 6; ++m6) {
            int m = grp*6 + m6;
            int c = (int)cand24[r*NCAND + m];
            const float4* xb4 = &x4[(size_t)(rbase + c)*16];
            float dot = 0.f;
#pragma unroll
            for (int i = 0; i < 8; ++i) {
                float4 a = xrA[i]; float4 b = xb4[i];
                dot = fmaf(a.x, b.x, dot); dot = fmaf(a.y, b.y, dot);
                dot = fmaf(a.z, b.z, dot); dot = fmaf(a.w, b.w, dot);
            }
#pragma unroll
            for (int i = 8; i < 16; ++i) {
                float4 a = x4[(size_t)(r0g + r)*16 + i]; float4 b = xb4[i];
                dot = fmaf(a.x, b.x, dot); dot = fmaf(a.y, b.y, dot);
                dot = fmaf(a.z, b.z, dot); dot = fmaf(a.w, b.w, dot);
            }
            float kd = __fsub_rn(__fadd_rn(sqr, sq[rbase + c]), __fmul_rn(2.0f, dot));
            kdf[r*68 + m] = kd;
            cand[r*68 + 32 + m] = (unsigned int)c;
        }
    }
    __syncthreads();

    // exact top-16 with (key, idx) ordering
    if (t < 64) {
        float* kdf = (float*)cand;
        float dk[KNN]; int di[KNN];
#pragma unroll
        for (int j = 0; j < KNN; ++j) { dk[j] = FLT_MAX; di[j] = 0x7fffffff; }
        for (int m = 0; m < NCAND; ++m) {
            float kd = kdf[t*68 + m];
            int c = (int)cand[t*68 + 32 + m];
            bool better = (kd < dk[KNN-1]) || (kd == dk[KNN-1] && c < di[KNN-1]);
            if (better) {
#pragma unroll
                for (int j = KNN-1; j >= 1; --j) {
                    bool sh = (dk[j-1] > kd) || (dk[j-1] == kd && di[j-1] > c);
                    bool pl = (!sh) && ((dk[j] > kd) || (dk[j] == kd && di[j] > c));
                    float nk = sh ? dk[j-1] : (pl ? kd : dk[j]);
                    int ni = sh ? di[j-1] : (pl ? c : di[j]);
                    dk[j] = nk; di[j] = ni;
                }
                if ((dk[0] > kd) || (dk[0] == kd && di[0] > c)) { dk[0] = kd; di[0] = c; }
            }
        }
#pragma unroll
        for (int k = 0; k < KNN; ++k) nbr[(size_t)(r0g + t)*16 + k] = di[k];
    }
}

// Kernel 3: out[n,o] = relu(out[n,o] + max_k Bv[nbr_k, o])   (out holds A from k1)
__global__ __launch_bounds__(256) void k_combine(const float* __restrict__ Bvv,
    const int* __restrict__ nbr, float* __restrict__ out)
{
    int t = threadIdx.x;
    int row = blockIdx.x*4 + (t >> 6);
    int o = t & 63;
    int rb = (row >> 11) << 11;
    float m = -FLT_MAX;
#pragma unroll
    for (int k = 0; k < 16; ++k) {
        int c = nbr[(size_t)row*16 + k];
        m = fmaxf(m, Bvv[(size_t)(rb + c)*64 + o]);
    }
    out[(size_t)row*64 + o] = fmaxf(out[(size_t)row*64 + o] + m, 0.f);
}

extern "C" void kernel_launch(void* const* d_in, const int* in_sizes, int n_in,
                              void* d_out, int out_size, void* d_ws, size_t ws_size,
                              hipStream_t stream) {
    const float* x    = (const float*)d_in[0];
    // d_in[1] = batch (contiguous per batch; unused)
    const float* w    = (const float*)d_in[2];
    const float* bias = (const float*)d_in[3];
    float* out = (float*)d_out;

    float* Bvv  = (float*)d_ws;                       // 32 MB
    float* sqnp = Bvv + (size_t)NTOT * 64;            // 0.5 MB
    int*   nbr  = (int*)(sqnp + NTOT);                // 8 MB
    unsigned int* xbu = (unsigned int*)(nbr + (size_t)NTOT * 16);   // 16 MB bf16 x

    k_transform<<<NTOT/256, 256, 0, stream>>>((const float4*)x, w, bias, out, Bvv, sqnp, (uint4*)xbu);
    k_topk<<<2048, 256, 0, stream>>>((const float4*)x, (const uint4*)xbu, sqnp, nbr);
    k_combine<<<NTOT/4, 256, 0, stream>>>(Bvv, nbr, out);
}

// Round 18
// 530.195 us; speedup vs baseline: 1.1301x; 1.0907x over previous
//
#include <hip/hip_runtime.h>
#include <cfloat>

#define BB 64
#define NPERB 2048
#define KNN 16
#define NTOT (BB*NPERB)
#define NCAND 24

typedef __bf16 bf16x8 __attribute__((ext_vector_type(8)));
typedef float  f32x4  __attribute__((ext_vector_type(4)));

__device__ __forceinline__ unsigned int med3u(unsigned int a, unsigned int b, unsigned int c) {
    unsigned int d;
    asm("v_med3_u32 %0, %1, %2, %3" : "=v"(d) : "v"(a), "v"(b), "v"(c));
    return d;
}

__device__ __forceinline__ unsigned short bf16rn(float f) {
    unsigned int u = __float_as_uint(f);
    u += 0x7fffu + ((u >> 16) & 1u);
    return (unsigned short)(u >> 16);
}
__device__ __forceinline__ unsigned int pk2(float a, float b) {
    return ((unsigned int)bf16rn(b) << 16) | (unsigned int)bf16rn(a);
}

// Kernel 1: R12-measured version (part of the 531us best). W staged in LDS
// [o][f], wave-uniform b128 broadcasts. (R13 lesson: weights-in-VGPR kills
// occupancy; R7/R8 lesson: per-(o,f) global w loads thrash L1.)
__global__ __launch_bounds__(256) void k_transform(const float4* __restrict__ x4,
    const float* __restrict__ w, const float* __restrict__ bias,
    float* __restrict__ Aout, float* __restrict__ Bvv, float* __restrict__ sqnp,
    uint4* __restrict__ xbu4)
{
    __shared__ __align__(16) float wm[64*64];    // (w1-w2)[o][f]
    __shared__ __align__(16) float w2m[64*64];   // w2[o][f]
    const int t = threadIdx.x;
    const int r = blockIdx.x * 256 + t;

#pragma unroll
    for (int i = 0; i < 16; ++i) {
        int e = t + i*256;
        int o = e >> 6, f = e & 63;
        float w1 = w[o*128 + f];
        float w2 = w[o*128 + 64 + f];
        wm[e]  = w1 - w2;
        w2m[e] = w2;
    }

    float xr[64];
#pragma unroll
    for (int j = 0; j < 16; ++j) {
        float4 v = x4[(size_t)r * 16 + j];
        xr[4*j+0] = v.x; xr[4*j+1] = v.y; xr[4*j+2] = v.z; xr[4*j+3] = v.w;
    }

    // numpy pairwise-order sum of squares (unchanged op tree)
    {
        float rr[8];
#pragma unroll
        for (int j = 0; j < 8; ++j) rr[j] = __fmul_rn(xr[j], xr[j]);
#pragma unroll
        for (int i = 1; i < 8; ++i)
#pragma unroll
            for (int j = 0; j < 8; ++j)
                rr[j] = __fadd_rn(rr[j], __fmul_rn(xr[8*i + j], xr[8*i + j]));
        float t01 = __fadd_rn(rr[0], rr[1]);
        float t23 = __fadd_rn(rr[2], rr[3]);
        float t45 = __fadd_rn(rr[4], rr[5]);
        float t67 = __fadd_rn(rr[6], rr[7]);
        sqnp[r] = __fadd_rn(__fadd_rn(t01, t23), __fadd_rn(t45, t67));
    }

    // bf16 copy (identical bytes)
#pragma unroll
    for (int i = 0; i < 8; ++i) {
        uint4 u;
        u.x = pk2(xr[8*i+0], xr[8*i+1]);
        u.y = pk2(xr[8*i+2], xr[8*i+3]);
        u.z = pk2(xr[8*i+4], xr[8*i+5]);
        u.w = pk2(xr[8*i+6], xr[8*i+7]);
        xbu4[(size_t)r * 8 + i] = u;
    }

    __syncthreads();   // weights staged

    for (int o = 0; o < 64; o += 4) {
        float a4[4], b4[4];
#pragma unroll
        for (int oo = 0; oo < 4; ++oo) {
            const float* wmr  = &wm [(o + oo)*64];
            const float* w2mr = &w2m[(o + oo)*64];
            float a1 = 0.f, a2 = 0.f;
#pragma unroll
            for (int fi = 0; fi < 16; ++fi) {
                f32x4 wa = *(const f32x4*)&wmr [fi*4];
                f32x4 wb = *(const f32x4*)&w2mr[fi*4];
#pragma unroll
                for (int k = 0; k < 4; ++k) {
                    float xv = xr[fi*4 + k];
                    a1 = __builtin_fmaf(xv, wa[k], a1);
                    a2 = __builtin_fmaf(xv, wb[k], a2);
                }
            }
            a4[oo] = __fadd_rn(a1, bias[o + oo]);
            b4[oo] = a2;
        }
        *(float4*)&Aout[(size_t)r * 64 + o] = make_float4(a4[0], a4[1], a4[2], a4[3]);
        *(float4*)&Bvv [(size_t)r * 64 + o] = make_float4(b4[0], b4[1], b4[2], b4[3]);
    }
}

// Kernel 2 (R15 edit, unmeasured): keep (256,5) — R14 A/B proved occupancy
// (42%) beats no-spill (35%): 366 vs 415us. New: SINGLE prefetch register set
// with write-early/issue-early iteration order:
//   barrier -> ds_write P(tile ct+1) -> issue P:=ct+2 -> compute(ct) -> barrier
// The previous barrier already drained P (vmcnt0 before s_barrier), so the
// ds_write never stalls, and each load still flies for one full compute
// (~1600cyc). ~9 fewer live VGPRs than R12's dual-set => spills should
// shrink toward zero at the 48-VGPR (256,5) allocation.
// Spill check: WRITE_SIZE (R12: 79.9MB) should drop to ~12-30MB.
__global__ __launch_bounds__(256, 5) void k_topk(const float4* __restrict__ x4,
    const uint4* __restrict__ xb, const float* __restrict__ sq, int* __restrict__ nbr)
{
    // phase1: bsh0 0..9216 | bsh1 9216..18432 | rsh 18432..27648 | sqc 27648..28160
    // phase2: cand 0..17408 | cand24 17408..20480
    __shared__ __align__(16) char smem[28160];
    unsigned short* bsh0 = (unsigned short*)smem;
    unsigned short* bsh1 = (unsigned short*)(smem + 9216);
    unsigned short* rsh  = (unsigned short*)(smem + 18432);
    float* sqc           = (float*)(smem + 27648);     // [2][64]
    unsigned int* cand   = (unsigned int*)smem;        // 64 rows x 68
    unsigned short* cand24 = (unsigned short*)(smem + 17408);

    int t = threadIdx.x;
    int lane = t & 63;
    int w = t >> 6;
    int ln = lane & 15, qd = lane >> 4;
    int batch = blockIdx.x >> 5;
    int strip = blockIdx.x & 31;
    int rbase = batch * NPERB;
    int r0g = rbase + strip * 64;

    unsigned int ks[16];
#pragma unroll
    for (int j = 0; j < 16; ++j) ks[j] = 0xFFFFFFFFu;

    // single prefetch set
    uint4 p0, p1; float sp;
    auto issue_load = [&](int ct_) {
        const uint4* src = xb + ((size_t)rbase + ct_*64) * 8;
        p0 = src[t]; p1 = src[t + 256];
        sp = (t < 64) ? sq[rbase + ct_*64 + t] : 0.f;
    };
    auto stage_write = [&](int buf_) {
        unsigned short* bnext = buf_ ? bsh1 : bsh0;
        *(uint4*)&bnext[(t >> 3)*72 + (t & 7)*8] = p0;
        int l1 = t + 256;
        *(uint4*)&bnext[(l1 >> 3)*72 + (l1 & 7)*8] = p1;
        if (t < 64) sqc[buf_*64 + t] = sp;
    };

    // --- prologue ---
    {
        const uint4* src = xb + (size_t)r0g * 8;
#pragma unroll
        for (int i = 0; i < 2; ++i) {
            int l = t + i*256;
            uint4 v = src[l];
            *(uint4*)&rsh[(l >> 3)*72 + (l & 7)*8] = v;
        }
    }
    issue_load(0);
    __syncthreads();                       // rsh visible; drains P=tile0
    bf16x8 rf0 = *(const bf16x8*)&rsh[(w*16 + ln)*72 + qd*8];
    bf16x8 rf1 = *(const bf16x8*)&rsh[(w*16 + ln)*72 + 32 + qd*8];
    float sqr16 = sq[r0g + w*16 + ln] + 16.f;
    stage_write(0);                        // tile0 -> bsh0, sqc[0]
    issue_load(1);                         // P := tile1
    __syncthreads();                       // drains P=tile1 (short flight, once)

    // --- main loop: invariant at top: buf[ct&1] = tile ct, P = tile ct+1 ---
    for (int ct = 0; ct < 32; ++ct) {
        if (ct < 31) stage_write((ct + 1) & 1);   // tile ct+1 -> other buf (free: P drained at prev barrier)
        if (ct < 30) issue_load(ct + 2);          // P := tile ct+2, flies across compute
        const unsigned short* bcur = (ct & 1) ? bsh1 : bsh0;
        const float* sqcur = sqc + (ct & 1)*64;
#pragma unroll
        for (int ct2 = 0; ct2 < 4; ++ct2) {
            int pt = ct2*16 + ln;
            bf16x8 a0 = *(const bf16x8*)&bcur[pt*72 + qd*8];
            bf16x8 a1 = *(const bf16x8*)&bcur[pt*72 + 32 + qd*8];
            f32x4 acc = {0.f, 0.f, 0.f, 0.f};
            acc = __builtin_amdgcn_mfma_f32_16x16x32_bf16(a0, rf0, acc, 0, 0, 0);
            acc = __builtin_amdgcn_mfma_f32_16x16x32_bf16(a1, rf1, acc, 0, 0, 0);
            f32x4 sc4 = *(const f32x4*)&sqcur[ct2*16 + qd*4];
            int idxb = ct*64 + ct2*16 + qd*4;
#pragma unroll
            for (int j = 0; j < 4; ++j) {
                float s = fmaf(-2.f, acc[j], sc4[j] + sqr16);   // > 0 always
                unsigned int u = (__float_as_uint(s) & 0xFFFFF800u) | (unsigned int)(idxb + j);
#pragma unroll
                for (int jj = 15; jj >= 1; --jj) ks[jj] = med3u(u, ks[jj-1], ks[jj]);
                ks[0] = min(ks[0], u);
            }
        }
        __syncthreads();
    }

    // dump per-lane keys
    {
        int r = w*16 + ln;
#pragma unroll
        for (int j = 0; j < 16; ++j) cand[r*68 + qd*16 + j] = ks[j];
    }
    __syncthreads();

    // merge to bf16-top-24 per row
    if (t < 64) {
        unsigned int m24[NCAND];
#pragma unroll
        for (int j = 0; j < NCAND; ++j) m24[j] = 0xFFFFFFFFu;
        for (int i = 0; i < 64; ++i) {
            unsigned int u = cand[t*68 + i];
#pragma unroll
            for (int jj = NCAND-1; jj >= 1; --jj) m24[jj] = med3u(u, m24[jj-1], m24[jj]);
            m24[0] = min(m24[0], u);
        }
#pragma unroll
        for (int j = 0; j < NCAND; ++j) cand24[t*NCAND + j] = (unsigned short)(m24[j] & 0x7FFu);
    }
    __syncthreads();

    // np-exact rescore (R6-verified chain): 4 groups x 6 candidates per row
    {
        int r = t & 63, grp = t >> 6;
        float sqr = sq[r0g + r];
        float4 xrA[8];
#pragma unroll
        for (int i = 0; i < 8; ++i) xrA[i] = x4[(size_t)(r0g + r)*16 + i];
        float* kdf = (float*)cand;
#pragma unroll
        for (int m6 = 0; m6 < 6; ++m6) {
            int m = grp*6 + m6;
            int c = (int)cand24[r*NCAND + m];
            const float4* xb4 = &x4[(size_t)(rbase + c)*16];
            float dot = 0.f;
#pragma unroll
            for (int i = 0; i < 8; ++i) {
                float4 a = xrA[i]; float4 b = xb4[i];
                dot = fmaf(a.x, b.x, dot); dot = fmaf(a.y, b.y, dot);
                dot = fmaf(a.z, b.z, dot); dot = fmaf(a.w, b.w, dot);
            }
#pragma unroll
            for (int i = 8; i < 16; ++i) {
                float4 a = x4[(size_t)(r0g + r)*16 + i]; float4 b = xb4[i];
                dot = fmaf(a.x, b.x, dot); dot = fmaf(a.y, b.y, dot);
                dot = fmaf(a.z, b.z, dot); dot = fmaf(a.w, b.w, dot);
            }
            float kd = __fsub_rn(__fadd_rn(sqr, sq[rbase + c]), __fmul_rn(2.0f, dot));
            kdf[r*68 + m] = kd;
            cand[r*68 + 32 + m] = (unsigned int)c;
        }
    }
    __syncthreads();

    // exact top-16 with (key, idx) ordering
    if (t < 64) {
        float* kdf = (float*)cand;
        float dk[KNN]; int di[KNN];
#pragma unroll
        for (int j = 0; j < KNN; ++j) { dk[j] = FLT_MAX; di[j] = 0x7fffffff; }
        for (int m = 0; m < NCAND; ++m) {
            float kd = kdf[t*68 + m];
            int c = (int)cand[t*68 + 32 + m];
            bool better = (kd < dk[KNN-1]) || (kd == dk[KNN-1] && c < di[KNN-1]);
            if (better) {
#pragma unroll
                for (int j = KNN-1; j >= 1; --j) {
                    bool sh = (dk[j-1] > kd) || (dk[j-1] == kd && di[j-1] > c);
                    bool pl = (!sh) && ((dk[j] > kd) || (dk[j] == kd && di[j] > c));
                    float nk = sh ? dk[j-1] : (pl ? kd : dk[j]);
                    int ni = sh ? di[j-1] : (pl ? c : di[j]);
                    dk[j] = nk; di[j] = ni;
                }
                if ((dk[0] > kd) || (dk[0] == kd && di[0] > c)) { dk[0] = kd; di[0] = c; }
            }
        }
#pragma unroll
        for (int k = 0; k < KNN; ++k) nbr[(size_t)(r0g + t)*16 + k] = di[k];
    }
}

// Kernel 3: out[n,o] = relu(out[n,o] + max_k Bv[nbr_k, o])   (out holds A from k1)
__global__ __launch_bounds__(256) void k_combine(const float* __restrict__ Bvv,
    const int* __restrict__ nbr, float* __restrict__ out)
{
    int t = threadIdx.x;
    int row = blockIdx.x*4 + (t >> 6);
    int o = t & 63;
    int rb = (row >> 11) << 11;
    float m = -FLT_MAX;
#pragma unroll
    for (int k = 0; k < 16; ++k) {
        int c = nbr[(size_t)row*16 + k];
        m = fmaxf(m, Bvv[(size_t)(rb + c)*64 + o]);
    }
    out[(size_t)row*64 + o] = fmaxf(out[(size_t)row*64 + o] + m, 0.f);
}

extern "C" void kernel_launch(void* const* d_in, const int* in_sizes, int n_in,
                              void* d_out, int out_size, void* d_ws, size_t ws_size,
                              hipStream_t stream) {
    const float* x    = (const float*)d_in[0];
    // d_in[1] = batch (contiguous per batch; unused)
    const float* w    = (const float*)d_in[2];
    const float* bias = (const float*)d_in[3];
    float* out = (float*)d_out;

    float* Bvv  = (float*)d_ws;                       // 32 MB
    float* sqnp = Bvv + (size_t)NTOT * 64;            // 0.5 MB
    int*   nbr  = (int*)(sqnp + NTOT);                // 8 MB
    unsigned int* xbu = (unsigned int*)(nbr + (size_t)NTOT * 16);   // 16 MB bf16 x

    k_transform<<<NTOT/256, 256, 0, stream>>>((const float4*)x, w, bias, out, Bvv, sqnp, (uint4*)xbu);
    k_topk<<<2048, 256, 0, stream>>>((const float4*)x, (const uint4*)xbu, sqnp, nbr);
    k_combine<<<NTOT/4, 256, 0, stream>>>(Bvv, nbr, out);
}